// Round 11
// baseline (3297.252 us; speedup 1.0000x reference)
//
#include <hip/hip_runtime.h>

typedef float  f32x4  __attribute__((ext_vector_type(4)));
typedef short  s16x8  __attribute__((ext_vector_type(8)));
typedef short  s16x4  __attribute__((ext_vector_type(4)));
typedef _Float16 f16;

namespace {
constexpr int NN = 127, IDIM = 300, HD = 150;
// persistent-W GEMM
constexpr int GNT = 512;             // 8 waves; wave owns 16-row M-tiles, all 15 col-tiles
constexpr int KSTR = 328;            // B [col][k] k-stride (shorts): 164 dw -> conflict-free b128
constexpr int HCOLS = 240;           // cols per half (480 padded / 2)
constexpr int WHALF_SH = HCOLS * KSTR;          // 78720 shorts = 157,440 B
constexpr int GEMM_LDS = WHALF_SH * 2;          // 157,440 B -> 1 block/CU
constexpr int NTILES = 32512;        // 520192 rows / 16
// lights
constexpr int LNT = 320;
constexpr int CSTR = 168;            // chs/hts stride: 84 dw, 16B-aligned rows

constexpr int W_SH = 2 * WHALF_SH;   // 157,440 shorts
constexpr int U_SH = 480 * 160;      // plain [col][k] bf16
constexpr int F_SH = 160 * 160;

// ws rings: c f16 [4096][126][152] | hb bf16 [4096][127][152] | iuo f16 [4096][127][456] | slabs
constexpr size_t C_N   = (size_t)4096 * 126 * 152;
constexpr size_t HB_N  = (size_t)4096 * 127 * 152;
constexpr size_t IUO_N = (size_t)4096 * 127 * 456;

__device__ __forceinline__ short f2bf(float f) {
    union { __bf16 b; short s; } u; u.b = (__bf16)f; return u.s;
}
__device__ __forceinline__ float bf2f(short s) {
    union { float f; unsigned u; } v; v.u = ((unsigned)(unsigned short)s) << 16; return v.f;
}
__device__ __forceinline__ float h2f_s(short s) {
    union { f16 h; short s; } u; u.s = s; return (float)u.h;
}
__device__ __forceinline__ short f2h_s(float f) {
    union { f16 h; short s; } u; u.h = (f16)f; return u.s;
}
__device__ __forceinline__ float sig_(float x)  { return 1.0f / (1.0f + __expf(-x)); }
__device__ __forceinline__ float tanh_(float x) { float e = __expf(2.0f * x); return 1.0f - 2.0f / (e + 1.0f); }
__device__ __forceinline__ s16x4 cvt4(float a,float b,float c,float d) {
    return s16x4{ f2bf(a), f2bf(b), f2bf(c), f2bf(d) };
}
__device__ __forceinline__ s16x8 cat(s16x4 lo, s16x4 hi) {
    return __builtin_shufflevector(lo, hi, 0,1,2,3,4,5,6,7);
}
__device__ __forceinline__ s16x8 cvt8f(float4 lo, float4 hi) {
    return cat(cvt4(lo.x,lo.y,lo.z,lo.w), cvt4(hi.x,hi.y,hi.z,hi.w));
}
__device__ __forceinline__ f32x4 MFMA(s16x8 a, s16x8 b, f32x4 c) {
    return __builtin_amdgcn_mfma_f32_16x16x32_bf16(a, b, c, 0, 0, 0);
}
typedef const __attribute__((address_space(1))) unsigned int* gp_t;
typedef __attribute__((address_space(3))) unsigned int* lp_t;
} // namespace

// -------- one-time weight prep: W -> 2 halves [240][KSTR]; U,F plain [col][160] --------
__global__ __launch_bounds__(256)
void prep_w(const float* __restrict__ Wiuo, const float* __restrict__ Uiuo,
            const float* __restrict__ Ufw, short* __restrict__ dst) {
    int i = blockIdx.x * 256 + threadIdx.x;
    short v = 0;
    if (i < W_SH) {
        int h = i / WHALF_SH, r = i - h * WHALF_SH;
        int col = r / KSTR, k = r - col * KSTR;
        int gcol = h * HCOLS + col;
        int g = gcol / 160, cp = gcol - g * 160;
        if (cp < HD && k < IDIM) v = f2bf(Wiuo[(size_t)(g*HD + cp)*IDIM + k]);
        dst[i] = v;
    } else if (i < W_SH + U_SH) {
        int q = i - W_SH;
        int col = q / 160, k = q - col * 160;
        int g = col / 160, cp = col - g * 160;
        if (cp < HD && k < HD) v = f2bf(Uiuo[(size_t)(g*HD + cp)*HD + k]);
        dst[i] = v;
    } else if (i < W_SH + U_SH + F_SH) {
        int q = i - W_SH - U_SH;
        int col = q / 160, k = q - col * 160;
        if (col < HD && k < HD) v = f2bf(Ufw[(size_t)col*HD + k]);
        dst[i] = v;
    }
}

// -------- persistent-W projection GEMM: W-half resident in LDS, ZERO barriers in M-loop --------
// Wave owns a 16-row M-tile (A per-lane from global x) x 15 col-tiles of its block's half.
// MFMA maps: A row=lane&15, B col=lane&15 (shared lane->k); C/D col=lane&15, row=4*(lane>>4)+reg.
__global__ __launch_bounds__(GNT)
void gemm_w(const float* __restrict__ x, const short* __restrict__ Wh,
            f16* __restrict__ iuo_all)
{
    extern __shared__ short Bs[];    // [240][KSTR]
    const int t = threadIdx.x, wv = t >> 6, ln = t & 63, l15 = ln & 15, kg = ln >> 4;
    const int kg8 = kg * 8;
    const int half = blockIdx.x & 1;
    const int idx  = blockIdx.x >> 1;

    // stage whole W-half once (9840 x 16B, linear)
    {
        const char* src = (const char*)(Wh + (size_t)half * WHALF_SH);
        char* dstl = (char*)Bs;
        for (int u = t; u < WHALF_SH / 8; u += GNT)
            __builtin_amdgcn_global_load_lds((gp_t)(src + (size_t)u * 16),
                                             (lp_t)(dstl + (size_t)u * 16), 16, 0, 0);
    }
    __syncthreads();

    // per-lane column info (static per thread)
    int gct[15], cigt[15];
    #pragma unroll
    for (int ct = 0; ct < 15; ++ct) {
        int col = half * HCOLS + ct * 16 + l15;
        gct[ct] = col / 160;
        cigt[ct] = col - gct[ct] * 160;
    }

    for (int m = idx * 8 + wv; m < NTILES; m += 2048) {
        const int row0 = m * 16;
        int d = 6;
        #pragma unroll
        for (int dd = 0; dd <= 5; ++dd)
            if (row0 >= 4096 * (128 - (2 << dd))) { d = dd; break; }
        const int base = 4096 * (128 - (2 << d));
        const int lg = d, mask = (1 << lg) - 1, start = (1 << lg) - 1;

        // A: 10 bf16 fragments per lane, loaded direct from global x
        const int lclA = row0 - base + l15;
        const float* xrow = x + ((size_t)(lclA >> lg) * NN + start + (lclA & mask)) * IDIM + kg8;
        s16x8 af[10];
        #pragma unroll
        for (int kc = 0; kc < 10; ++kc) {
            const int kb = kc * 32;
            const float4 z = {0.f, 0.f, 0.f, 0.f};
            float4 lo = (kb + kg8 + 4 <= IDIM) ? *(const float4*)(xrow + kb)     : z;
            float4 hi = (kb + kg8 + 8 <= IDIM) ? *(const float4*)(xrow + kb + 4) : z;
            af[kc] = cvt8f(lo, hi);
        }

        f32x4 acc[15] = {};
        #pragma unroll
        for (int kc = 0; kc < 10; ++kc) {
            #pragma unroll
            for (int ct = 0; ct < 15; ++ct) {
                const short* pb = &Bs[(ct * 16 + l15) * KSTR + kc * 32 + kg8];
                s16x8 bf = cat(*(const s16x4*)pb, *(const s16x4*)(pb + 4));
                acc[ct] = MFMA(af[kc], bf, acc[ct]);
            }
        }

        // epilogue: write pre-activations (f16) to node-indexed iuo ring
        #pragma unroll
        for (int r = 0; r < 4; ++r) {
            const int lcl = row0 - base + 4 * kg + r;
            const int b = lcl >> lg, s = lcl & mask;
            f16* ip = iuo_all + ((size_t)b * 127 + start + s) * 456;
            #pragma unroll
            for (int ct = 0; ct < 15; ++ct)
                if (cigt[ct] < HD)
                    ip[152 * gct[ct] + cigt[ct]] = (f16)acc[ct][r];
        }
    }
}

// -------- leaf gates: elementwise fuse over leaf rows (memory-bound) --------
__global__ __launch_bounds__(256)
void leaf_gates(const f16* __restrict__ iuo_all, const float* __restrict__ biuo,
                float* __restrict__ h_all, f16* __restrict__ c_ring,
                short* __restrict__ hb)
{
    const int idx = blockIdx.x * 256 + threadIdx.x;     // (row, seg): 262144 rows x 19 segs
    if (idx >= 262144 * 19) return;
    const int row = idx / 19, seg = idx - row * 19;
    const int b = row >> 6, s = row & 63;
    const int c0 = seg * 8;
    const f16* ip = iuo_all + ((size_t)b * 127 + 63 + s) * 456 + c0;
    s16x8 iv = *(const s16x8*)(ip);
    s16x8 uv = *(const s16x8*)(ip + 152);
    s16x8 ov = *(const s16x8*)(ip + 304);

    float* hp = h_all + ((size_t)b * 127 + 63 + s) * HD;
    f16*   cp = c_ring + ((size_t)b * 126 + 62 + s) * 152 + c0;
    short* bp = hb + ((size_t)b * 127 + 63 + s) * 152 + c0;
    s16x8 cb, hbv;
    #pragma unroll
    for (int e = 0; e < 8; ++e) {
        int c = c0 + e;
        float cn = 0.f, hn = 0.f;
        if (c < HD) {
            float ig = h2f_s(((const s16x8&)iv)[e]) + biuo[c];
            float ug = h2f_s(((const s16x8&)uv)[e]) + biuo[HD + c];
            float og = h2f_s(((const s16x8&)ov)[e]) + biuo[2*HD + c];
            cn = sig_(ig) * tanh_(ug);
            hn = sig_(og) * tanh_(cn);
            hp[c] = hn;
        }
        cb[e]  = f2h_s(cn);
        hbv[e] = f2bf(hn);
    }
    *(s16x4*)cp       = s16x4{cb[0], cb[1], cb[2], cb[3]};
    *(s16x4*)(cp + 4) = s16x4{cb[4], cb[5], cb[6], cb[7]};
    *(s16x4*)bp       = s16x4{hbv[0], hbv[1], hbv[2], hbv[3]};
    *(s16x4*)(bp + 4) = s16x4{hbv[4], hbv[5], hbv[6], hbv[7]};
}

// -------- light: per internal level. 32 parents/block, 5 waves x 2 col-triples --------
__global__ __launch_bounds__(LNT, 4)
void lvl_light(const short* __restrict__ Ubf, const short* __restrict__ Fbf,
               const float* __restrict__ biuo, const float* __restrict__ Ufb,
               const f16* __restrict__ iuo_all, f16* __restrict__ c_ring,
               float* __restrict__ h_all, short* __restrict__ hb,
               int start, int lg, int cstart)
{
    __shared__ short chs[2][32][CSTR];    // [child][parent][k] bf16
    __shared__ short hts[32][CSTR];       // h_tilda
    __shared__ short fgs[5][64][34];      // per-wave f-gates

    const int t = threadIdx.x;
    const int wv = t >> 6, ln = t & 63, l15 = ln & 15, kg = ln >> 4;
    const int row0 = blockIdx.x * 32;
    const int mask = (1 << lg) - 1;
    const int ct0 = 16 * (2*wv)     + l15;
    const int ct1 = 16 * (2*wv + 1) + l15;

    // stage children h from bf16 hb ring (straight copy, 16B chunks)
    for (int idx = t; idx < 64 * 19; idx += LNT) {
        int rw = idx / 19, seg = idx - rw * 19;
        int plane = rw >> 5, lr = rw & 31;
        int row = row0 + lr, b = row >> lg, s = row & mask;
        const short* hp = hb + ((size_t)b*127 + cstart + 2*s + plane) * 152 + seg * 8;
        *(s16x8*)&chs[plane][lr][seg * 8] = *(const s16x8*)hp;
    }
    if (t < 64) {   // zero pad k [152,160)
        int plane = t >> 5, lr = t & 31;
        *(s16x8*)&chs[plane][lr][152] = s16x8{0,0,0,0,0,0,0,0};
    }
    __syncthreads();

    // h_tilda once: (r, seg) = one 16-elem chunk per thread (32x10 = 320)
    {
        int r = t / 10, sg = t - 10 * (t / 10);
        int k0 = sg * 16;
        s16x8 h0a = *(const s16x8*)&chs[0][r][k0];
        s16x8 h0b = *(const s16x8*)&chs[0][r][k0 + 8];
        s16x8 h1a = *(const s16x8*)&chs[1][r][k0];
        s16x8 h1b = *(const s16x8*)&chs[1][r][k0 + 8];
        s16x8 oa, ob;
        #pragma unroll
        for (int e = 0; e < 8; ++e) {
            oa[e] = f2bf(bf2f(h0a[e]) + bf2f(h1a[e]));
            ob[e] = f2bf(bf2f(h0b[e]) + bf2f(h1b[e]));
        }
        *(s16x8*)&hts[r][k0]     = oa;
        *(s16x8*)&hts[r][k0 + 8] = ob;
    }

    // F phase: f = sigmoid(ch @ F^T + b)
    f32x4 facc[4][2] = {};
    #pragma unroll
    for (int kc = 0; kc < 5; ++kc) {
        int ka = kc * 32 + kg * 8;
        s16x8 af[4];
        #pragma unroll
        for (int rt = 0; rt < 4; ++rt) {
            const short* p = &chs[rt >> 1][(rt & 1) * 16 + l15][ka];
            af[rt] = cat(*(const s16x4*)p, *(const s16x4*)(p + 4));
        }
        #pragma unroll
        for (int tt = 0; tt < 2; ++tt) {
            int ct = tt ? ct1 : ct0;
            s16x8 bf = *(const s16x8*)(Fbf + (size_t)ct * 160 + ka);
            #pragma unroll
            for (int rt = 0; rt < 4; ++rt)
                facc[rt][tt] = MFMA(af[rt], bf, facc[rt][tt]);
        }
    }
    #pragma unroll
    for (int tt = 0; tt < 2; ++tt) {
        int ct = tt ? ct1 : ct0;
        float fb_ = (ct < HD) ? Ufb[ct] : 0.0f;
        #pragma unroll
        for (int rt = 0; rt < 4; ++rt)
            #pragma unroll
            for (int r = 0; r < 4; ++r)
                fgs[wv][rt*16 + 4*kg + r][tt*16 + l15] = f2bf(sig_(facc[rt][tt][r] + fb_));
    }
    __syncthreads();

    // U phase: acc = h_tilda @ U^T
    f32x4 acc[2][2][3] = {};
    #pragma unroll
    for (int kc = 0; kc < 5; ++kc) {
        int ka = kc * 32 + kg * 8;
        s16x8 hs[2];
        #pragma unroll
        for (int mt = 0; mt < 2; ++mt) {
            const short* p = &hts[16*mt + l15][ka];
            hs[mt] = cat(*(const s16x4*)p, *(const s16x4*)(p + 4));
        }
        #pragma unroll
        for (int tt = 0; tt < 2; ++tt) {
            int ct = tt ? ct1 : ct0;
            #pragma unroll
            for (int g = 0; g < 3; ++g) {
                s16x8 bf = *(const s16x8*)(Ubf + (size_t)(g*160 + ct) * 160 + ka);
                #pragma unroll
                for (int mt = 0; mt < 2; ++mt)
                    acc[mt][tt][g] = MFMA(hs[mt], bf, acc[mt][tt][g]);
            }
        }
    }

    // epilogue
    #pragma unroll
    for (int tt = 0; tt < 2; ++tt) {
        int c = tt ? ct1 : ct0;
        float bi = 0.f, bu = 0.f, bo = 0.f;
        if (c < HD) { bi = biuo[c]; bu = biuo[HD + c]; bo = biuo[2*HD + c]; }
        #pragma unroll
        for (int mt = 0; mt < 2; ++mt)
            #pragma unroll
            for (int r = 0; r < 4; ++r) {
                int pl = 16*mt + 4*kg + r;
                int row = row0 + pl, b = row >> lg, s = row & mask;
                size_t nrow = (size_t)b*127 + start + s;
                if (c < HD) {
                    const f16* ip = iuo_all + nrow * 456;
                    float ig = (float)ip[c]       + bi + acc[mt][tt][0][r];
                    float ug = (float)ip[152 + c] + bu + acc[mt][tt][1][r];
                    float og = (float)ip[304 + c] + bo + acc[mt][tt][2][r];
                    float f0 = bf2f(fgs[wv][pl][tt*16 + l15]);
                    float f1 = bf2f(fgs[wv][32 + pl][tt*16 + l15]);
                    size_t ci = ((size_t)b*126 + cstart + 2*s - 1) * 152 + c;
                    float c0 = (float)c_ring[ci];
                    float c1 = (float)c_ring[ci + 152];
                    float cn = sig_(ig) * tanh_(ug) + f0*c0 + f1*c1;
                    float hn = sig_(og) * tanh_(cn);
                    h_all[nrow * HD + c] = hn;
                    hb[nrow * 152 + c] = f2bf(hn);
                    if (start > 0)
                        c_ring[((size_t)b*126 + start + s - 1) * 152 + c] = (f16)cn;
                } else if (c < 152) {
                    hb[nrow * 152 + c] = 0;    // keep hb pad zeroed for next level
                }
            }
    }
}

extern "C" void kernel_launch(void* const* d_in, const int* in_sizes, int n_in,
                              void* d_out, int out_size, void* d_ws, size_t ws_size,
                              hipStream_t stream) {
    const float* x    = (const float*)d_in[0];
    const float* Wiuo = (const float*)d_in[1];
    const float* Uiuo = (const float*)d_in[2];
    const float* biuo = (const float*)d_in[3];
    const float* Ufw  = (const float*)d_in[4];
    const float* Ufb  = (const float*)d_in[5];
    float* h = (float*)d_out;

    f16*   c_ring  = (f16*)d_ws;
    short* hb      = (short*)(c_ring + C_N);
    f16*   iuo_all = (f16*)(hb + HB_N);
    short* slabs   = (short*)(iuo_all + IUO_N);
    const short* Wh  = slabs;
    const short* Ubf = slabs + W_SH;
    const short* Fbf = slabs + W_SH + U_SH;

    (void)hipFuncSetAttribute((const void*)gemm_w,
                              hipFuncAttributeMaxDynamicSharedMemorySize, 160 * 1024);

    prep_w<<<(W_SH + U_SH + F_SH + 255) / 256, 256, 0, stream>>>(Wiuo, Uiuo, Ufw, slabs);

    gemm_w<<<512, GNT, GEMM_LDS, stream>>>(x, Wh, iuo_all);

    leaf_gates<<<(262144 * 19 + 255) / 256, 256, 0, stream>>>(iuo_all, biuo, h, c_ring, hb);

    for (int d = 5; d >= 0; --d) {
        const int start = (1 << d) - 1, cstart = (1 << (d+1)) - 1;
        lvl_light<<<128 << d, LNT, 0, stream>>>(Ubf, Fbf, biuo, Ufb, iuo_all, c_ring, h, hb,
                                                start, d, cstart);
    }
}

// Round 12
// 1404.277 us; speedup vs baseline: 2.3480x; 2.3480x over previous
//
#include <hip/hip_runtime.h>

typedef float  f32x4  __attribute__((ext_vector_type(4)));
typedef short  s16x8  __attribute__((ext_vector_type(8)));
typedef short  s16x4  __attribute__((ext_vector_type(4)));
typedef _Float16 f16;

namespace {
constexpr int NN = 127, IDIM = 300, HD = 150;
constexpr int GNT = 512;             // gemm: 8 waves; wave: ct=wv&3, row-half=wv>>2
constexpr int KSTR = 328;            // A/B k-stride (shorts): 164 dw -> 2-way banks (free)
constexpr int SLAB_SH = 64 * KSTR;   // 20,992 sh = 41,984 B = 41 KiB-chunks exactly
constexpr int GEMM_LDS = 3 * SLAB_SH * 2;   // A + B dbuf = 125,952 B -> 1 block/CU
constexpr int LNT = 320;
constexpr int CSTR = 168;            // light chs/hts stride

constexpr int W_SH = 9 * SLAB_SH;    // [triple t][gate g][64 cols][328]
constexpr int U_SH = 480 * 160;      // plain [col][k]
constexpr int F_SH = 160 * 160;

// ws rings: c f16 [4096][126][152] | hb bf16 [4096][127][152] | iuo f16 [4096][63][456] | slabs
constexpr size_t C_N   = (size_t)4096 * 126 * 152;
constexpr size_t HB_N  = (size_t)4096 * 127 * 152;
constexpr size_t IUO_N = (size_t)4096 * 63 * 456;

__device__ __forceinline__ short f2bf(float f) {
    union { __bf16 b; short s; } u; u.b = (__bf16)f; return u.s;
}
__device__ __forceinline__ float bf2f(short s) {
    union { float f; unsigned u; } v; v.u = ((unsigned)(unsigned short)s) << 16; return v.f;
}
__device__ __forceinline__ float sig_(float x)  { return 1.0f / (1.0f + __expf(-x)); }
__device__ __forceinline__ float tanh_(float x) { float e = __expf(2.0f * x); return 1.0f - 2.0f / (e + 1.0f); }
__device__ __forceinline__ s16x4 cvt4(float a,float b,float c,float d) {
    return s16x4{ f2bf(a), f2bf(b), f2bf(c), f2bf(d) };
}
__device__ __forceinline__ s16x8 cat(s16x4 lo, s16x4 hi) {
    return __builtin_shufflevector(lo, hi, 0,1,2,3,4,5,6,7);
}
__device__ __forceinline__ s16x8 cvt8f(float4 lo, float4 hi) {
    return cat(cvt4(lo.x,lo.y,lo.z,lo.w), cvt4(hi.x,hi.y,hi.z,hi.w));
}
__device__ __forceinline__ f32x4 MFMA(s16x8 a, s16x8 b, f32x4 c) {
    return __builtin_amdgcn_mfma_f32_16x16x32_bf16(a, b, c, 0, 0, 0);
}
typedef const __attribute__((address_space(1))) unsigned int* gp_t;
typedef __attribute__((address_space(3))) unsigned int* lp_t;
__device__ __forceinline__ void stage_slab(const short* g, short* l, int wv, int ln) {
    const char* gb = (const char*)g;
    char* lb = (char*)l;
    for (int c = wv; c < 41; c += 8)
        __builtin_amdgcn_global_load_lds((gp_t)(gb + c * 1024 + ln * 16),
                                         (lp_t)(lb + c * 1024 + ln * 16), 16, 0, 0);
}
} // namespace

// -------- one-time weight prep --------
__global__ __launch_bounds__(256)
void prep_w(const float* __restrict__ Wiuo, const float* __restrict__ Uiuo,
            const float* __restrict__ Ufw, short* __restrict__ dst) {
    int i = blockIdx.x * 256 + threadIdx.x;
    short v = 0;
    if (i < W_SH) {
        int q = i / SLAB_SH, r = i - q * SLAB_SH;
        int t = q / 3, g = q - t * 3;
        int cc = r / KSTR, k = r - cc * KSTR;
        int cig = t * 64 + cc;
        if (cig < HD && k < IDIM) v = f2bf(Wiuo[(size_t)(g*HD + cig)*IDIM + k]);
        dst[i] = v;
    } else if (i < W_SH + U_SH) {
        int q = i - W_SH;
        int col = q / 160, k = q - col * 160;
        int g = col / 160, cp = col - g * 160;
        if (cp < HD && k < HD) v = f2bf(Uiuo[(size_t)(g*HD + cp)*HD + k]);
        dst[i] = v;
    } else if (i < W_SH + U_SH + F_SH) {
        int q = i - W_SH - U_SH;
        int col = q / 160, k = q - col * 160;
        if (col < HD && k < HD) v = f2bf(Ufw[(size_t)col*HD + k]);
        dst[i] = v;
    }
}

// -------- projection GEMM: A in regs, 9 gate-aligned B slabs (dbuf), fused leaf gates --------
// MFMA maps: A row=lane&15, B col=lane&15 (shared lane->k); C/D col=lane&15, row=4*(lane>>4)+reg.
__global__ __launch_bounds__(GNT, 2)
void big_gemm(const float* __restrict__ x, const short* __restrict__ Wsl,
              const float* __restrict__ biuo, float* __restrict__ h_all,
              f16* __restrict__ c_ring, short* __restrict__ hb,
              f16* __restrict__ iuo_all)
{
    extern __shared__ short smem[];
    short* As = smem;                    // [64][328]
    short* B0 = smem + SLAB_SH;          // dbuf
    const int t = threadIdx.x, wv = t >> 6, ln = t & 63, l15 = ln & 15, kg = ln >> 4;
    const int kg8 = kg * 8, ct = wv & 3, rh = wv >> 2;
    const int row0 = blockIdx.x * 64;

    int d = 6;
    #pragma unroll
    for (int dd = 0; dd <= 5; ++dd)
        if (row0 >= 4096 * (128 - (2 << dd))) { d = dd; break; }
    const int base = 4096 * (128 - (2 << d));
    const int lg = d, mask = (1 << lg) - 1, start = (1 << lg) - 1;
    const int local0 = row0 - base;

    // prologue: issue B slab 0, stage A (64 rows x 328 sh, zero-padded)
    stage_slab(Wsl, B0, wv, ln);
    for (int u = t; u < 64 * 41; u += GNT) {
        int row = u / 41, uu = u - row * 41;
        int k0 = uu * 8;
        int lcl = local0 + row, b = lcl >> lg, s = lcl & mask;
        const float* xp = x + ((size_t)b * NN + start + s) * IDIM + k0;
        const float4 z = {0.f, 0.f, 0.f, 0.f};
        float4 lo = (k0 + 4 <= IDIM) ? *(const float4*)(xp)     : z;
        float4 hi = (k0 + 8 <= IDIM) ? *(const float4*)(xp + 4) : z;
        *(s16x8*)&As[row * KSTR + k0] = cvt8f(lo, hi);
    }
    __syncthreads();

    // A fragments to registers: af[mt][kc], rows 32*rh + 16*mt + l15
    s16x8 af[2][10];
    #pragma unroll
    for (int mt = 0; mt < 2; ++mt)
        #pragma unroll
        for (int kc = 0; kc < 10; ++kc) {
            const short* p = &As[(32*rh + 16*mt + l15) * KSTR + kc*32 + kg8];
            af[mt][kc] = cat(*(const s16x4*)p, *(const s16x4*)(p + 4));
        }

    const int c = ct * 16 + l15;     // within-gate col offset base (+64*t per triple)
    #pragma unroll
    for (int tr = 0; tr < 3; ++tr) {
        f32x4 acc[3][2] = {};        // [gate][mt]
        #pragma unroll
        for (int g = 0; g < 3; ++g) {
            const int q = tr * 3 + g;
            __syncthreads();         // buf (q&1) reads done (q-2) & DMA(q) landed
            if (q < 8)
                stage_slab(Wsl + (q+1) * SLAB_SH, B0 + ((q+1) & 1) * SLAB_SH, wv, ln);
            const short* Bc = B0 + (q & 1) * SLAB_SH;
            #pragma unroll
            for (int kc = 0; kc < 10; ++kc) {
                const short* pb = &Bc[(ct*16 + l15) * KSTR + kc*32 + kg8];
                s16x8 bf = cat(*(const s16x4*)pb, *(const s16x4*)(pb + 4));
                acc[g][0] = MFMA(af[0][kc], bf, acc[g][0]);
                acc[g][1] = MFMA(af[1][kc], bf, acc[g][1]);
            }
        }
        // epilogue for this triple's cols: cig = tr*64 + c
        const int cig = tr * 64 + c;
        if (d == 6) {
            #pragma unroll
            for (int mt = 0; mt < 2; ++mt)
                #pragma unroll
                for (int r = 0; r < 4; ++r) {
                    int lcl = local0 + 32*rh + 16*mt + 4*kg + r;
                    int b = lcl >> 6, s = lcl & 63;
                    if (cig < HD) {
                        float ig = acc[0][mt][r] + biuo[cig];
                        float ug = acc[1][mt][r] + biuo[HD + cig];
                        float og = acc[2][mt][r] + biuo[2*HD + cig];
                        float cn = sig_(ig) * tanh_(ug);
                        float hn = sig_(og) * tanh_(cn);
                        h_all[((size_t)b*NN + 63 + s) * HD + cig] = hn;
                        c_ring[((size_t)b*126 + 62 + s) * 152 + cig] = (f16)cn;
                        hb[((size_t)b*127 + 63 + s) * 152 + cig] = f2bf(hn);
                    } else if (cig < 152) {
                        hb[((size_t)b*127 + 63 + s) * 152 + cig] = 0;
                    }
                }
        } else if (cig < HD) {
            #pragma unroll
            for (int mt = 0; mt < 2; ++mt)
                #pragma unroll
                for (int r = 0; r < 4; ++r) {
                    int lcl = local0 + 32*rh + 16*mt + 4*kg + r;
                    int b = lcl >> lg, s = lcl & mask;
                    f16* ip = iuo_all + ((size_t)b*63 + start + s) * 456;
                    ip[cig]       = (f16)acc[0][mt][r];
                    ip[152 + cig] = (f16)acc[1][mt][r];
                    ip[304 + cig] = (f16)acc[2][mt][r];
                }
        }
    }
}

// -------- light: per internal level. 32 parents/block, 5 waves x 2 col-triples --------
__global__ __launch_bounds__(LNT, 4)
void lvl_light(const short* __restrict__ Ubf, const short* __restrict__ Fbf,
               const float* __restrict__ biuo, const float* __restrict__ Ufb,
               const f16* __restrict__ iuo_all, f16* __restrict__ c_ring,
               float* __restrict__ h_all, short* __restrict__ hb,
               int start, int lg, int cstart)
{
    __shared__ short chs[2][32][CSTR];
    __shared__ short hts[32][CSTR];
    __shared__ short fgs[5][64][34];

    const int t = threadIdx.x;
    const int wv = t >> 6, ln = t & 63, l15 = ln & 15, kg = ln >> 4;
    const int row0 = blockIdx.x * 32;
    const int mask = (1 << lg) - 1;
    const int ct0 = 16 * (2*wv)     + l15;
    const int ct1 = 16 * (2*wv + 1) + l15;

    for (int idx = t; idx < 64 * 19; idx += LNT) {
        int rw = idx / 19, seg = idx - rw * 19;
        int plane = rw >> 5, lr = rw & 31;
        int row = row0 + lr, b = row >> lg, s = row & mask;
        const short* hp = hb + ((size_t)b*127 + cstart + 2*s + plane) * 152 + seg * 8;
        *(s16x8*)&chs[plane][lr][seg * 8] = *(const s16x8*)hp;
    }
    if (t < 64) {
        int plane = t >> 5, lr = t & 31;
        *(s16x8*)&chs[plane][lr][152] = s16x8{0,0,0,0,0,0,0,0};
    }
    __syncthreads();

    {
        int r = t / 10, sg = t - 10 * (t / 10);
        int k0 = sg * 16;
        s16x8 h0a = *(const s16x8*)&chs[0][r][k0];
        s16x8 h0b = *(const s16x8*)&chs[0][r][k0 + 8];
        s16x8 h1a = *(const s16x8*)&chs[1][r][k0];
        s16x8 h1b = *(const s16x8*)&chs[1][r][k0 + 8];
        s16x8 oa, ob;
        #pragma unroll
        for (int e = 0; e < 8; ++e) {
            oa[e] = f2bf(bf2f(h0a[e]) + bf2f(h1a[e]));
            ob[e] = f2bf(bf2f(h0b[e]) + bf2f(h1b[e]));
        }
        *(s16x8*)&hts[r][k0]     = oa;
        *(s16x8*)&hts[r][k0 + 8] = ob;
    }

    f32x4 facc[4][2] = {};
    #pragma unroll
    for (int kc = 0; kc < 5; ++kc) {
        int ka = kc * 32 + kg * 8;
        s16x8 af[4];
        #pragma unroll
        for (int rt = 0; rt < 4; ++rt) {
            const short* p = &chs[rt >> 1][(rt & 1) * 16 + l15][ka];
            af[rt] = cat(*(const s16x4*)p, *(const s16x4*)(p + 4));
        }
        #pragma unroll
        for (int tt = 0; tt < 2; ++tt) {
            int ct = tt ? ct1 : ct0;
            s16x8 bf = *(const s16x8*)(Fbf + (size_t)ct * 160 + ka);
            #pragma unroll
            for (int rt = 0; rt < 4; ++rt)
                facc[rt][tt] = MFMA(af[rt], bf, facc[rt][tt]);
        }
    }
    #pragma unroll
    for (int tt = 0; tt < 2; ++tt) {
        int ct = tt ? ct1 : ct0;
        float fb_ = (ct < HD) ? Ufb[ct] : 0.0f;
        #pragma unroll
        for (int rt = 0; rt < 4; ++rt)
            #pragma unroll
            for (int r = 0; r < 4; ++r)
                fgs[wv][rt*16 + 4*kg + r][tt*16 + l15] = f2bf(sig_(facc[rt][tt][r] + fb_));
    }
    __syncthreads();

    f32x4 acc[2][2][3] = {};
    #pragma unroll
    for (int kc = 0; kc < 5; ++kc) {
        int ka = kc * 32 + kg * 8;
        s16x8 hs[2];
        #pragma unroll
        for (int mt = 0; mt < 2; ++mt) {
            const short* p = &hts[16*mt + l15][ka];
            hs[mt] = cat(*(const s16x4*)p, *(const s16x4*)(p + 4));
        }
        #pragma unroll
        for (int tt = 0; tt < 2; ++tt) {
            int ct = tt ? ct1 : ct0;
            #pragma unroll
            for (int g = 0; g < 3; ++g) {
                s16x8 bf = *(const s16x8*)(Ubf + (size_t)(g*160 + ct) * 160 + ka);
                #pragma unroll
                for (int mt = 0; mt < 2; ++mt)
                    acc[mt][tt][g] = MFMA(hs[mt], bf, acc[mt][tt][g]);
            }
        }
    }

    #pragma unroll
    for (int tt = 0; tt < 2; ++tt) {
        int c = tt ? ct1 : ct0;
        float bi = 0.f, bu = 0.f, bo = 0.f;
        if (c < HD) { bi = biuo[c]; bu = biuo[HD + c]; bo = biuo[2*HD + c]; }
        #pragma unroll
        for (int mt = 0; mt < 2; ++mt)
            #pragma unroll
            for (int r = 0; r < 4; ++r) {
                int pl = 16*mt + 4*kg + r;
                int row = row0 + pl, b = row >> lg, s = row & mask;
                size_t nrow = (size_t)b*127 + start + s;
                if (c < HD) {
                    const f16* ip = iuo_all + ((size_t)b*63 + start + s) * 456;
                    float ig = (float)ip[c]       + bi + acc[mt][tt][0][r];
                    float ug = (float)ip[152 + c] + bu + acc[mt][tt][1][r];
                    float og = (float)ip[304 + c] + bo + acc[mt][tt][2][r];
                    float f0 = bf2f(fgs[wv][pl][tt*16 + l15]);
                    float f1 = bf2f(fgs[wv][32 + pl][tt*16 + l15]);
                    size_t ci = ((size_t)b*126 + cstart + 2*s - 1) * 152 + c;
                    float c0 = (float)c_ring[ci];
                    float c1 = (float)c_ring[ci + 152];
                    float cn = sig_(ig) * tanh_(ug) + f0*c0 + f1*c1;
                    float hn = sig_(og) * tanh_(cn);
                    h_all[nrow * HD + c] = hn;
                    hb[nrow * 152 + c] = f2bf(hn);
                    if (start > 0)
                        c_ring[((size_t)b*126 + start + s - 1) * 152 + c] = (f16)cn;
                } else if (c < 152) {
                    hb[nrow * 152 + c] = 0;
                }
            }
    }
}

extern "C" void kernel_launch(void* const* d_in, const int* in_sizes, int n_in,
                              void* d_out, int out_size, void* d_ws, size_t ws_size,
                              hipStream_t stream) {
    const float* x    = (const float*)d_in[0];
    const float* Wiuo = (const float*)d_in[1];
    const float* Uiuo = (const float*)d_in[2];
    const float* biuo = (const float*)d_in[3];
    const float* Ufw  = (const float*)d_in[4];
    const float* Ufb  = (const float*)d_in[5];
    float* h = (float*)d_out;

    f16*   c_ring  = (f16*)d_ws;
    short* hb      = (short*)(c_ring + C_N);
    f16*   iuo_all = (f16*)(hb + HB_N);
    short* slabs   = (short*)(iuo_all + IUO_N);
    const short* Wsl = slabs;
    const short* Ubf = slabs + W_SH;
    const short* Fbf = slabs + W_SH + U_SH;

    (void)hipFuncSetAttribute((const void*)big_gemm,
                              hipFuncAttributeMaxDynamicSharedMemorySize, 160 * 1024);

    prep_w<<<(W_SH + U_SH + F_SH + 255) / 256, 256, 0, stream>>>(Wiuo, Uiuo, Ufw, slabs);

    big_gemm<<<8128, GNT, GEMM_LDS, stream>>>(x, Wsl, biuo, h, c_ring, hb, iuo_all);

    for (int d = 5; d >= 0; --d) {
        const int start = (1 << d) - 1, cstart = (1 << (d+1)) - 1;
        lvl_light<<<128 << d, LNT, 0, stream>>>(Ubf, Fbf, biuo, Ufb, iuo_all, c_ring, h, hb,
                                                start, d, cstart);
    }
}

// Round 13
// 1166.245 us; speedup vs baseline: 2.8272x; 1.2041x over previous
//
#include <hip/hip_runtime.h>

typedef float  f32x4  __attribute__((ext_vector_type(4)));
typedef short  s16x8  __attribute__((ext_vector_type(8)));
typedef short  s16x4  __attribute__((ext_vector_type(4)));
typedef _Float16 f16;

namespace {
constexpr int NN = 127, IDIM = 300, HD = 150;
constexpr int GNT = 640;             // gemm: 10 waves; wave wv owns col-triple wv (cols 16wv+l15 of each gate)
constexpr int XSTR = 324;            // A stride (shorts): 162 dw -> 2-way banks (free)
constexpr int BCS  = 36;             // B col stride (shorts): 18 dw -> 16-bank spread
constexpr int SLAB_SH = 17408;       // 480*36=17280 + pad = 34 KiB
constexpr int SCH = 34;              // 1-KiB staging chunks per slab
constexpr int A_SH = 64 * XSTR;      // 20736 shorts
constexpr int GEMM_LDS = (A_SH + 2 * SLAB_SH) * 2;   // 111,104 B -> 1 block/CU
constexpr int LNT = 320;
constexpr int CSTR = 168;            // light chs/hts stride

constexpr int W_SH = 10 * SLAB_SH;   // [kc][col][36]
constexpr int U_SH = 480 * 160;      // plain [col][k]
constexpr int F_SH = 160 * 160;

// ws rings: c f16 [4096][126][152] | hb bf16 [4096][127][152] | iuo f16 [4096][63][456] | slabs
constexpr size_t C_N   = (size_t)4096 * 126 * 152;
constexpr size_t HB_N  = (size_t)4096 * 127 * 152;
constexpr size_t IUO_N = (size_t)4096 * 63 * 456;

__device__ __forceinline__ short f2bf(float f) {
    union { __bf16 b; short s; } u; u.b = (__bf16)f; return u.s;
}
__device__ __forceinline__ float bf2f(short s) {
    union { float f; unsigned u; } v; v.u = ((unsigned)(unsigned short)s) << 16; return v.f;
}
__device__ __forceinline__ float sig_(float x)  { return 1.0f / (1.0f + __expf(-x)); }
__device__ __forceinline__ float tanh_(float x) { float e = __expf(2.0f * x); return 1.0f - 2.0f / (e + 1.0f); }
__device__ __forceinline__ s16x4 cvt4(float a,float b,float c,float d) {
    return s16x4{ f2bf(a), f2bf(b), f2bf(c), f2bf(d) };
}
__device__ __forceinline__ s16x8 cat(s16x4 lo, s16x4 hi) {
    return __builtin_shufflevector(lo, hi, 0,1,2,3,4,5,6,7);
}
__device__ __forceinline__ f32x4 MFMA(s16x8 a, s16x8 b, f32x4 c) {
    return __builtin_amdgcn_mfma_f32_16x16x32_bf16(a, b, c, 0, 0, 0);
}
typedef const __attribute__((address_space(1))) unsigned int* gp_t;
typedef __attribute__((address_space(3))) unsigned int* lp_t;
__device__ __forceinline__ void stage_slab(const short* g, short* l, int wv, int ln) {
    const char* gb = (const char*)g;
    char* lb = (char*)l;
    for (int c = wv; c < SCH; c += 10)
        __builtin_amdgcn_global_load_lds((gp_t)(gb + c * 1024 + ln * 16),
                                         (lp_t)(lb + c * 1024 + ln * 16), 16, 0, 0);
}
} // namespace

// -------- one-time weight prep: W -> 10 K-chunk slabs [480][36]; U,F plain [col][160] --------
__global__ __launch_bounds__(256)
void prep_w(const float* __restrict__ Wiuo, const float* __restrict__ Uiuo,
            const float* __restrict__ Ufw, short* __restrict__ dst) {
    int i = blockIdx.x * 256 + threadIdx.x;
    short v = 0;
    if (i < W_SH) {
        int kc = i / SLAB_SH, r = i - kc * SLAB_SH;
        if (r < 480 * BCS) {
            int col = r / BCS, j = r - col * BCS;
            int g = col / 160, cp = col - g * 160, k = kc * 32 + j;
            if (cp < HD && j < 32 && k < IDIM) v = f2bf(Wiuo[(size_t)(g*HD + cp)*IDIM + k]);
        }
        dst[i] = v;
    } else if (i < W_SH + U_SH) {
        int q = i - W_SH;
        int col = q / 160, k = q - col * 160;
        int g = col / 160, cp = col - g * 160;
        if (cp < HD && k < HD) v = f2bf(Uiuo[(size_t)(g*HD + cp)*HD + k]);
        dst[i] = v;
    } else if (i < W_SH + U_SH + F_SH) {
        int q = i - W_SH - U_SH;
        int col = q / 160, k = q - col * 160;
        if (col < HD && k < HD) v = f2bf(Ufw[(size_t)col*HD + k]);
        dst[i] = v;
    }
}

// -------- merged projection GEMM (R7 structure, A prologue-staged) --------
// Per chunk: issue B-DMA(kc+1) -> A,B ds_reads + 12 MFMA -> barrier (drains DMA issued
// one full chunk earlier). A never touches the loop.
// MFMA maps: A row=lane&15, B col=lane&15 (shared lane->k); C/D col=lane&15, row=4*(lane>>4)+reg.
__global__ __launch_bounds__(GNT)
void big_gemm(const float* __restrict__ x, const short* __restrict__ Wsl,
              const float* __restrict__ biuo, float* __restrict__ h_all,
              f16* __restrict__ c_ring, short* __restrict__ hb,
              f16* __restrict__ iuo_all)
{
    extern __shared__ short smem[];
    short* As = smem;                // [64][324]
    short* B0 = smem + A_SH;
    short* B1 = B0 + SLAB_SH;

    const int t = threadIdx.x;
    const int wv = t >> 6, ln = t & 63, l15 = ln & 15, kg = ln >> 4;
    const int kg8 = kg * 8;
    const int row0 = blockIdx.x * 64;

    int d = 6;
    #pragma unroll
    for (int dd = 0; dd <= 5; ++dd)
        if (row0 >= 4096 * (128 - (2 << dd))) { d = dd; break; }
    const int base = 4096 * (128 - (2 << d));
    const int lg = d, mask = (1 << lg) - 1, start = (1 << lg) - 1;
    const int local0 = row0 - base;

    // prologue: issue B slab 0, stage A fully (coalesced float4 -> bf16 quads)
    stage_slab(Wsl, B0, wv, ln);
    {
        constexpr int NQ = XSTR / 4;     // 81 quads/row
        for (int u = t; u < 64 * NQ; u += GNT) {
            int row = u / NQ, q = u - row * NQ;
            int k0 = q * 4;
            int lcl = local0 + row, b = lcl >> lg, s = lcl & mask;
            s16x4 v = {0,0,0,0};
            if (k0 + 4 <= IDIM) {
                float4 f = *(const float4*)(x + ((size_t)b * NN + start + s) * IDIM + k0);
                v = cvt4(f.x, f.y, f.z, f.w);
            }
            *(s16x4*)&As[row * XSTR + k0] = v;
        }
    }
    __syncthreads();                 // A visible; slab-0 DMA drained

    f32x4 acc[4][3] = {};            // [row-tile mt][gate g]
    #pragma unroll
    for (int kc = 0; kc < 10; ++kc) {
        const short* Bc = (kc & 1) ? B1 : B0;
        short* Bn       = (kc & 1) ? B0 : B1;
        if (kc < 9)
            stage_slab(Wsl + (kc + 1) * SLAB_SH, Bn, wv, ln);

        s16x8 a[4];
        #pragma unroll
        for (int mt = 0; mt < 4; ++mt) {
            const short* p = &As[(16*mt + l15) * XSTR + kc * 32 + kg8];
            a[mt] = cat(*(const s16x4*)p, *(const s16x4*)(p + 4));
        }
        #pragma unroll
        for (int g = 0; g < 3; ++g) {
            const short* pb = &Bc[(g*160 + 16*wv + l15) * BCS + kg8];
            s16x8 bf = cat(*(const s16x4*)pb, *(const s16x4*)(pb + 4));
            #pragma unroll
            for (int mt = 0; mt < 4; ++mt)
                acc[mt][g] = MFMA(a[mt], bf, acc[mt][g]);
        }
        __syncthreads();             // B(kc) readers done; DMA(kc+1) has a full chunk to land
    }

    // epilogue: wave owns column c of every gate -> in-register gate fusion
    const int c = 16 * wv + l15;     // 0..159
    if (d == 6) {
        float bi = 0.f, bu = 0.f, bo = 0.f;
        if (c < HD) { bi = biuo[c]; bu = biuo[HD + c]; bo = biuo[2*HD + c]; }
        #pragma unroll
        for (int mt = 0; mt < 4; ++mt)
            #pragma unroll
            for (int r = 0; r < 4; ++r) {
                int lcl = local0 + 16*mt + 4*kg + r;
                int b = lcl >> 6, s = lcl & 63;
                size_t nrow = (size_t)b * 127 + 63 + s;
                if (c < HD) {
                    float cn = sig_(acc[mt][0][r] + bi) * tanh_(acc[mt][1][r] + bu);
                    float hn = sig_(acc[mt][2][r] + bo) * tanh_(cn);
                    h_all[nrow * HD + c] = hn;
                    c_ring[((size_t)b * 126 + 62 + s) * 152 + c] = (f16)cn;
                    hb[nrow * 152 + c] = f2bf(hn);
                } else if (c < 152) {
                    hb[nrow * 152 + c] = 0;
                }
            }
    } else if (c < HD) {
        #pragma unroll
        for (int mt = 0; mt < 4; ++mt)
            #pragma unroll
            for (int r = 0; r < 4; ++r) {
                int lcl = local0 + 16*mt + 4*kg + r;
                int b = lcl >> lg, s = lcl & mask;
                f16* ip = iuo_all + ((size_t)b * 63 + start + s) * 456;
                ip[c]       = (f16)acc[mt][0][r];
                ip[152 + c] = (f16)acc[mt][1][r];
                ip[304 + c] = (f16)acc[mt][2][r];
            }
    }
}

// -------- light: per internal level. 32 parents/block, 5 waves x 2 col-triples --------
__global__ __launch_bounds__(LNT, 4)
void lvl_light(const short* __restrict__ Ubf, const short* __restrict__ Fbf,
               const float* __restrict__ biuo, const float* __restrict__ Ufb,
               const f16* __restrict__ iuo_all, f16* __restrict__ c_ring,
               float* __restrict__ h_all, short* __restrict__ hb,
               int start, int lg, int cstart)
{
    __shared__ short chs[2][32][CSTR];
    __shared__ short hts[32][CSTR];
    __shared__ short fgs[5][64][34];

    const int t = threadIdx.x;
    const int wv = t >> 6, ln = t & 63, l15 = ln & 15, kg = ln >> 4;
    const int row0 = blockIdx.x * 32;
    const int mask = (1 << lg) - 1;
    const int ct0 = 16 * (2*wv)     + l15;
    const int ct1 = 16 * (2*wv + 1) + l15;

    for (int idx = t; idx < 64 * 19; idx += LNT) {
        int rw = idx / 19, seg = idx - rw * 19;
        int plane = rw >> 5, lr = rw & 31;
        int row = row0 + lr, b = row >> lg, s = row & mask;
        const short* hp = hb + ((size_t)b*127 + cstart + 2*s + plane) * 152 + seg * 8;
        *(s16x8*)&chs[plane][lr][seg * 8] = *(const s16x8*)hp;
    }
    if (t < 64) {
        int plane = t >> 5, lr = t & 31;
        *(s16x8*)&chs[plane][lr][152] = s16x8{0,0,0,0,0,0,0,0};
    }
    __syncthreads();

    {
        int r = t / 10, sg = t - 10 * (t / 10);
        int k0 = sg * 16;
        s16x8 h0a = *(const s16x8*)&chs[0][r][k0];
        s16x8 h0b = *(const s16x8*)&chs[0][r][k0 + 8];
        s16x8 h1a = *(const s16x8*)&chs[1][r][k0];
        s16x8 h1b = *(const s16x8*)&chs[1][r][k0 + 8];
        s16x8 oa, ob;
        #pragma unroll
        for (int e = 0; e < 8; ++e) {
            oa[e] = f2bf(bf2f(h0a[e]) + bf2f(h1a[e]));
            ob[e] = f2bf(bf2f(h0b[e]) + bf2f(h1b[e]));
        }
        *(s16x8*)&hts[r][k0]     = oa;
        *(s16x8*)&hts[r][k0 + 8] = ob;
    }

    f32x4 facc[4][2] = {};
    #pragma unroll
    for (int kc = 0; kc < 5; ++kc) {
        int ka = kc * 32 + kg * 8;
        s16x8 af[4];
        #pragma unroll
        for (int rt = 0; rt < 4; ++rt) {
            const short* p = &chs[rt >> 1][(rt & 1) * 16 + l15][ka];
            af[rt] = cat(*(const s16x4*)p, *(const s16x4*)(p + 4));
        }
        #pragma unroll
        for (int tt = 0; tt < 2; ++tt) {
            int ct = tt ? ct1 : ct0;
            s16x8 bf = *(const s16x8*)(Fbf + (size_t)ct * 160 + ka);
            #pragma unroll
            for (int rt = 0; rt < 4; ++rt)
                facc[rt][tt] = MFMA(af[rt], bf, facc[rt][tt]);
        }
    }
    #pragma unroll
    for (int tt = 0; tt < 2; ++tt) {
        int ct = tt ? ct1 : ct0;
        float fb_ = (ct < HD) ? Ufb[ct] : 0.0f;
        #pragma unroll
        for (int rt = 0; rt < 4; ++rt)
            #pragma unroll
            for (int r = 0; r < 4; ++r)
                fgs[wv][rt*16 + 4*kg + r][tt*16 + l15] = f2bf(sig_(facc[rt][tt][r] + fb_));
    }
    __syncthreads();

    f32x4 acc[2][2][3] = {};
    #pragma unroll
    for (int kc = 0; kc < 5; ++kc) {
        int ka = kc * 32 + kg * 8;
        s16x8 hs[2];
        #pragma unroll
        for (int mt = 0; mt < 2; ++mt) {
            const short* p = &hts[16*mt + l15][ka];
            hs[mt] = cat(*(const s16x4*)p, *(const s16x4*)(p + 4));
        }
        #pragma unroll
        for (int tt = 0; tt < 2; ++tt) {
            int ct = tt ? ct1 : ct0;
            #pragma unroll
            for (int g = 0; g < 3; ++g) {
                s16x8 bf = *(const s16x8*)(Ubf + (size_t)(g*160 + ct) * 160 + ka);
                #pragma unroll
                for (int mt = 0; mt < 2; ++mt)
                    acc[mt][tt][g] = MFMA(hs[mt], bf, acc[mt][tt][g]);
            }
        }
    }

    #pragma unroll
    for (int tt = 0; tt < 2; ++tt) {
        int c = tt ? ct1 : ct0;
        float bi = 0.f, bu = 0.f, bo = 0.f;
        if (c < HD) { bi = biuo[c]; bu = biuo[HD + c]; bo = biuo[2*HD + c]; }
        #pragma unroll
        for (int mt = 0; mt < 2; ++mt)
            #pragma unroll
            for (int r = 0; r < 4; ++r) {
                int pl = 16*mt + 4*kg + r;
                int row = row0 + pl, b = row >> lg, s = row & mask;
                size_t nrow = (size_t)b*127 + start + s;
                if (c < HD) {
                    const f16* ip = iuo_all + ((size_t)b*63 + start + s) * 456;
                    float ig = (float)ip[c]       + bi + acc[mt][tt][0][r];
                    float ug = (float)ip[152 + c] + bu + acc[mt][tt][1][r];
                    float og = (float)ip[304 + c] + bo + acc[mt][tt][2][r];
                    float f0 = bf2f(fgs[wv][pl][tt*16 + l15]);
                    float f1 = bf2f(fgs[wv][32 + pl][tt*16 + l15]);
                    size_t ci = ((size_t)b*126 + cstart + 2*s - 1) * 152 + c;
                    float c0 = (float)c_ring[ci];
                    float c1 = (float)c_ring[ci + 152];
                    float cn = sig_(ig) * tanh_(ug) + f0*c0 + f1*c1;
                    float hn = sig_(og) * tanh_(cn);
                    h_all[nrow * HD + c] = hn;
                    hb[nrow * 152 + c] = f2bf(hn);
                    if (start > 0)
                        c_ring[((size_t)b*126 + start + s - 1) * 152 + c] = (f16)cn;
                } else if (c < 152) {
                    hb[nrow * 152 + c] = 0;
                }
            }
    }
}

extern "C" void kernel_launch(void* const* d_in, const int* in_sizes, int n_in,
                              void* d_out, int out_size, void* d_ws, size_t ws_size,
                              hipStream_t stream) {
    const float* x    = (const float*)d_in[0];
    const float* Wiuo = (const float*)d_in[1];
    const float* Uiuo = (const float*)d_in[2];
    const float* biuo = (const float*)d_in[3];
    const float* Ufw  = (const float*)d_in[4];
    const float* Ufb  = (const float*)d_in[5];
    float* h = (float*)d_out;

    f16*   c_ring  = (f16*)d_ws;
    short* hb      = (short*)(c_ring + C_N);
    f16*   iuo_all = (f16*)(hb + HB_N);
    short* slabs   = (short*)(iuo_all + IUO_N);
    const short* Wsl = slabs;
    const short* Ubf = slabs + W_SH;
    const short* Fbf = slabs + W_SH + U_SH;

    (void)hipFuncSetAttribute((const void*)big_gemm,
                              hipFuncAttributeMaxDynamicSharedMemorySize, 160 * 1024);

    prep_w<<<(W_SH + U_SH + F_SH + 255) / 256, 256, 0, stream>>>(Wiuo, Uiuo, Ufw, slabs);

    big_gemm<<<8128, GNT, GEMM_LDS, stream>>>(x, Wsl, biuo, h, c_ring, hb, iuo_all);

    for (int d = 5; d >= 0; --d) {
        const int start = (1 << d) - 1, cstart = (1 << (d+1)) - 1;
        lvl_light<<<128 << d, LNT, 0, stream>>>(Ubf, Fbf, biuo, Ufb, iuo_all, c_ring, h, hb,
                                                start, d, cstart);
    }
}